// Round 1
// baseline (25225.507 us; speedup 1.0000x reference)
//
#include <hip/hip_runtime.h>
#include <stdint.h>

typedef uint16_t u16;
typedef __attribute__((ext_vector_type(8))) short bf16x8;   // 8 bf16 in 4 VGPRs
typedef __attribute__((ext_vector_type(4))) float f32x4;

#define DEVI __device__ __forceinline__

DEVI u16 f2b(float f) {                       // f32 -> bf16 RNE
  uint32_t u = __float_as_uint(f);
  uint32_t r = (u + 0x7fffu + ((u >> 16) & 1u)) >> 16;
  return (u16)r;
}
DEVI float b2f(u16 h) { return __uint_as_float(((uint32_t)h) << 16); }

typedef const __attribute__((address_space(1))) uint32_t* gptr_t;
typedef __attribute__((address_space(3))) uint32_t* lptr_t;
DEVI void gload_lds16(const void* g, void* l) {
  // async global->LDS, 16B per lane; LDS dest = wave-uniform base + lane*16
  __builtin_amdgcn_global_load_lds((gptr_t)g, (lptr_t)l, 16, 0, 0);
}

// ---------------------------------------------------------------- converts
__global__ void cvt_f32_bf16(const float* __restrict__ in, u16* __restrict__ out, long n) {
  long i = ((long)blockIdx.x * blockDim.x + threadIdx.x) * 4;
  long stride = (long)gridDim.x * blockDim.x * 4;
  for (; i < n; i += stride) {
    float4 v = *(const float4*)(in + i);
    ushort4 o;
    o.x = f2b(v.x); o.y = f2b(v.y); o.z = f2b(v.z); o.w = f2b(v.w);
    *(ushort4*)(out + i) = o;
  }
}

__global__ void init_h(const float* __restrict__ h0, float* __restrict__ hf, u16* __restrict__ hb) {
  int i = blockIdx.x * blockDim.x + threadIdx.x;   // grid covers exactly 2*64*1024
  float v = h0[i];
  hf[i] = v;
  hb[i] = f2b(v);
}

// ---------------------------------------------------------------- GEMM
// C[m,n] = sum_k A[m,k]*W[n,k] + bias[n],  A:[M,K] bf16, W:[N,K] bf16 (B^T layout)
// M=32768, N=6144 fixed; tile 128x128, BK=64, 256 thr = 4 waves, wave = 64x64.
__global__ __launch_bounds__(256) void gemm_bt_bias(
    const u16* __restrict__ A, const u16* __restrict__ W,
    const float* __restrict__ bias, u16* __restrict__ C, int K) {
  constexpr int NLD = 6144;
  __shared__ u16 As[128 * 64];   // rows of 64 bf16 = 128B, XOR-swizzled 16B slots
  __shared__ u16 Bs[128 * 64];
  const int t = threadIdx.x;
  const int l = t & 63, w = t >> 6;
  const int lr = l & 15, lk = l >> 4;
  const long bm = (long)blockIdx.y * 128;
  const long bn = (long)blockIdx.x * 128;
  const int wm = (w >> 1) * 64, wn = (w & 1) * 64;

  f32x4 acc[4][4] = {};

  for (int k0 = 0; k0 < K; k0 += 64) {
    __syncthreads();   // prior compute done before re-staging
    #pragma unroll
    for (int i = 0; i < 4; ++i) {
      int slot = i * 256 + t;
      int row = slot >> 3, s = slot & 7;
      int c8 = (s ^ (row & 7)) * 8;    // pre-swizzled global source (rule #21)
      char* la = (char*)As + (size_t)(i * 256 + w * 64) * 16;  // wave-uniform base
      char* lb = (char*)Bs + (size_t)(i * 256 + w * 64) * 16;
      gload_lds16(A + (bm + row) * K + k0 + c8, la);
      gload_lds16(W + (bn + row) * K + k0 + c8, lb);
    }
    asm volatile("s_waitcnt vmcnt(0)" ::: "memory");
    __syncthreads();
    #pragma unroll
    for (int kk = 0; kk < 2; ++kk) {
      bf16x8 af[4], bfr[4];
      #pragma unroll
      for (int mi = 0; mi < 4; ++mi) {
        int row = wm + mi * 16 + lr;
        int sl = (kk * 4 + lk) ^ (row & 7);
        af[mi] = *(const bf16x8*)((const char*)As + row * 128 + sl * 16);
      }
      #pragma unroll
      for (int ni = 0; ni < 4; ++ni) {
        int row = wn + ni * 16 + lr;
        int sl = (kk * 4 + lk) ^ (row & 7);
        bfr[ni] = *(const bf16x8*)((const char*)Bs + row * 128 + sl * 16);
      }
      #pragma unroll
      for (int mi = 0; mi < 4; ++mi)
        #pragma unroll
        for (int ni = 0; ni < 4; ++ni)
          acc[mi][ni] = __builtin_amdgcn_mfma_f32_16x16x32_bf16(af[mi], bfr[ni], acc[mi][ni], 0, 0, 0);
    }
  }

  float bv[4];
  #pragma unroll
  for (int ni = 0; ni < 4; ++ni) bv[ni] = bias[bn + wn + ni * 16 + lr];
  #pragma unroll
  for (int mi = 0; mi < 4; ++mi)
    #pragma unroll
    for (int ni = 0; ni < 4; ++ni) {
      long col = bn + wn + ni * 16 + lr;
      #pragma unroll
      for (int j = 0; j < 4; ++j) {
        long row = bm + wm + mi * 16 + lk * 4 + j;   // C/D: row=(l>>4)*4+j, col=l&15
        C[row * NLD + col] = f2b(acc[mi][ni][j] + bv[ni]);
      }
    }
}

// ---------------------------------------------------------------- GRU step
// One time step, both directions. grid = 256 (dir(2) x rowhalf(2) x coltile(64)),
// block = 128 (2 waves). Wave: 16 batch rows x 16 hidden cols, 3 MFMA chains
// (r/z/n gate) over K=1024, fused gate math in-register.
__global__ __launch_bounds__(128) void gru_step(
    const u16* __restrict__ hb_in, const float* __restrict__ hf_in,
    float* __restrict__ hf_out, u16* __restrict__ hb_out,
    const u16* __restrict__ Whh,   // [2,3072,1024] bf16 (this layer)
    const float* __restrict__ bhh, // [2,3072] f32 (this layer)
    const u16* __restrict__ gx,    // [32768,6144] bf16
    u16* __restrict__ y_b, float* __restrict__ y_f,  // one non-null
    int t) {
  const int bid = blockIdx.x;
  const int c = bid & 63;          // col tile -> XCD = c%8 (L2-resident W slice)
  const int rh = (bid >> 6) & 1;
  const int dir = bid >> 7;
  const int l = threadIdx.x & 63, w = threadIdx.x >> 6;
  const int lr = l & 15, lk = l >> 4;
  const int r0 = rh * 32 + w * 16;
  const int j0 = c * 16;

  const u16* aptr = hb_in + (size_t)((dir << 6) + r0 + lr) * 1024 + lk * 8;
  const u16* bptr = Whh + ((size_t)dir * 3072 + j0 + lr) * 1024 + lk * 8;

  f32x4 aR = {0.f, 0.f, 0.f, 0.f}, aZ = {0.f, 0.f, 0.f, 0.f}, aN = {0.f, 0.f, 0.f, 0.f};
  #pragma unroll 8
  for (int kk = 0; kk < 32; ++kk) {
    bf16x8 av = *(const bf16x8*)(aptr + kk * 32);
    bf16x8 vr = *(const bf16x8*)(bptr + kk * 32);
    bf16x8 vz = *(const bf16x8*)(bptr + 1024 * 1024 + kk * 32);
    bf16x8 vn = *(const bf16x8*)(bptr + 2048 * 1024 + kk * 32);
    aR = __builtin_amdgcn_mfma_f32_16x16x32_bf16(av, vr, aR, 0, 0, 0);
    aZ = __builtin_amdgcn_mfma_f32_16x16x32_bf16(av, vz, aZ, 0, 0, 0);
    aN = __builtin_amdgcn_mfma_f32_16x16x32_bf16(av, vn, aN, 0, 0, 0);
  }

  const int jg = j0 + lr;
  const float* bh = bhh + dir * 3072;
  const float bhr = bh[jg], bhz = bh[1024 + jg], bhn = bh[2048 + jg];
  const int tt = dir ? (511 - t) : t;
  #pragma unroll
  for (int j = 0; j < 4; ++j) {
    int b = r0 + lk * 4 + j;
    size_t grow = (size_t)(tt * 64 + b) * 6144 + (size_t)dir * 3072 + jg;
    float gxr = b2f(gx[grow]);
    float gxz = b2f(gx[grow + 1024]);
    float gxn = b2f(gx[grow + 2048]);
    size_t hidx = (size_t)((dir << 6) + b) * 1024 + jg;
    float hp = hf_in[hidx];
    float rg = 1.f / (1.f + __expf(-(gxr + aR[j] + bhr)));
    float zg = 1.f / (1.f + __expf(-(gxz + aZ[j] + bhz)));
    float ng = tanhf(gxn + rg * (aN[j] + bhn));
    float hn = (1.f - zg) * ng + zg * hp;
    hf_out[hidx] = hn;
    hb_out[hidx] = f2b(hn);
    size_t yidx = (size_t)(tt * 64 + b) * 2048 + (size_t)dir * 1024 + jg;
    if (y_b) y_b[yidx] = f2b(hn);
    else     y_f[yidx] = hn;
  }
}

// ---------------------------------------------------------------- launch
extern "C" void kernel_launch(void* const* d_in, const int* in_sizes, int n_in,
                              void* d_out, int out_size, void* d_ws, size_t ws_size,
                              hipStream_t stream) {
  (void)in_sizes; (void)n_in; (void)out_size; (void)ws_size;
  const float* x     = (const float*)d_in[0];   // [512,64,1024]
  const float* h0    = (const float*)d_in[1];   // [6,64,1024]
  const float* w_ih0 = (const float*)d_in[2];   // [2,3072,1024]
  const float* w_ih  = (const float*)d_in[3];   // [2,2,3072,2048]
  const float* w_hh  = (const float*)d_in[4];   // [3,2,3072,1024]
  const float* b_ih  = (const float*)d_in[5];   // [3,2,3072]
  const float* b_hh  = (const float*)d_in[6];   // [3,2,3072]
  float* out = (float*)d_out;                   // [512,64,2048]

  char* p = (char*)d_ws;
  u16* wA    = (u16*)p; p += (size_t)32768 * 2048 * 2;       // layer input bf16
  u16* wGx   = (u16*)p; p += (size_t)32768 * 6144 * 2;       // gate preacts bf16
  u16* wWih0 = (u16*)p; p += (size_t)6144 * 1024 * 2;
  u16* wWih  = (u16*)p; p += (size_t)2 * 6144 * 2048 * 2;
  u16* wWhh  = (u16*)p; p += (size_t)6 * 3072 * 1024 * 2;
  float* wHf0 = (float*)p; p += (size_t)2 * 64 * 1024 * 4;
  float* wHf1 = (float*)p; p += (size_t)2 * 64 * 1024 * 4;
  u16* wHb0  = (u16*)p; p += (size_t)2 * 64 * 1024 * 2;
  u16* wHb1  = (u16*)p; p += (size_t)2 * 64 * 1024 * 2;

  cvt_f32_bf16<<<2048, 256, 0, stream>>>(x,     wA,    (long)33554432);
  cvt_f32_bf16<<<2048, 256, 0, stream>>>(w_ih0, wWih0, (long)6291456);
  cvt_f32_bf16<<<2048, 256, 0, stream>>>(w_ih,  wWih,  (long)25165824);
  cvt_f32_bf16<<<2048, 256, 0, stream>>>(w_hh,  wWhh,  (long)18874368);

  float* hf[2] = {wHf0, wHf1};
  u16*   hb[2] = {wHb0, wHb1};

  for (int layer = 0; layer < 3; ++layer) {
    int K = (layer == 0) ? 1024 : 2048;
    const u16* Wg = (layer == 0) ? wWih0 : (wWih + (size_t)(layer - 1) * 6144 * 2048);
    gemm_bt_bias<<<dim3(48, 256), 256, 0, stream>>>(wA, Wg, b_ih + (size_t)layer * 6144, wGx, K);
    init_h<<<512, 256, 0, stream>>>(h0 + (size_t)layer * 131072, hf[0], hb[0]);

    const u16* Whh_l  = wWhh + (size_t)layer * 2 * 3072 * 1024;
    const float* bhh_l = b_hh + (size_t)layer * 6144;
    u16*   yb = (layer < 2) ? wA : nullptr;
    float* yf = (layer < 2) ? nullptr : out;
    int cur = 0;
    for (int t = 0; t < 512; ++t) {
      gru_step<<<256, 128, 0, stream>>>(hb[cur], hf[cur], hf[cur ^ 1], hb[cur ^ 1],
                                        Whh_l, bhh_l, wGx, yb, yf, t);
      cur ^= 1;
    }
  }
}